// Round 9
// baseline (422.232 us; speedup 1.0000x reference)
//
#include <hip/hip_runtime.h>

#define BATCH 1024
#define NNODE 92
#define FIN   1024
#define FOUT  512

typedef float    f32x4 __attribute__((ext_vector_type(4)));
typedef _Float16 half8 __attribute__((ext_vector_type(8)));
typedef _Float16 half4 __attribute__((ext_vector_type(4)));

__device__ __forceinline__ float lrelu(float x) { return fmaxf(x, 0.2f * x); }

#define BAR_LGKM() do {                                                        \
    asm volatile("s_waitcnt lgkmcnt(0)" ::: "memory");                         \
    __builtin_amdgcn_sched_barrier(0);                                         \
    __builtin_amdgcn_s_barrier();                                              \
  } while (0)

// ---------------------------------------------------------------------------
// prep: WT[n][k] = f16(W[k][n]);  ATp[j][k] = f16(A[k][j]) padded [96][104]
// ---------------------------------------------------------------------------
__global__ __launch_bounds__(256) void prep_kernel(
    const float* __restrict__ W, const float* __restrict__ Am,
    _Float16* __restrict__ WT, _Float16* __restrict__ ATp) {
  int bid = blockIdx.x, t = threadIdx.x;
  if (bid < 64) {
    int n0 = bid * 8;
    for (int it = 0; it < 4; ++it) {
      int k = it * 256 + t;
      const f32x4* src = (const f32x4*)(W + (size_t)k * FOUT + n0);
      f32x4 v0 = src[0], v1 = src[1];
      #pragma unroll
      for (int c = 0; c < 4; ++c) {
        WT[(size_t)(n0 + c) * FIN + k]     = (_Float16)v0[c];
        WT[(size_t)(n0 + 4 + c) * FIN + k] = (_Float16)v1[c];
      }
    }
  } else {
    int j0 = (bid - 64) * 24;
    for (int idx = t; idx < 24 * 104; idx += 256) {
      int jr = idx / 104, k = idx - jr * 104;
      int j = j0 + jr;
      float v = (j < NNODE && k < NNODE) ? Am[k * NNODE + j] : 0.f;
      ATp[j * 104 + k] = (_Float16)v;
    }
  }
}

// ---------------------------------------------------------------------------
// K1: Wh = X @ W. 1472 blocks x 512 thr, tile 64m x 512n (X read ONCE).
//     8 waves, each 64m x 64n, acc 64 VGPR. BK=32.
//     B: global->reg DIRECT from L2-resident WT (no LDS, no glds); single
//        bf set refreshed right after MFMA (1 phase of L2 slack).
//     X: 3-deep register rotation (X(kt+3) issued at phase kt) -> 2 phases
//        of HBM slack; never drained at a barrier.
//     A: only LDS user (8 KB dbuf, swizzled); barrier = lgkmcnt(0) only.
//     Epilogue: fused Wh1/Wh2 + direct half4 Wh[b][f][96] stores (92%4==0).
// ---------------------------------------------------------------------------
__global__ __launch_bounds__(512, 4) void gemm_kernel(
    const float* __restrict__ X, const _Float16* __restrict__ WT,
    const float* __restrict__ av, _Float16* __restrict__ Wh,
    float* __restrict__ Wh1g, float* __restrict__ Wh2g) {
  __shared__ __align__(16) _Float16 Al0[64 * 32];   // 4096 B, swizzled
  __shared__ __align__(16) _Float16 Al1[64 * 32];
  __shared__ float red[64 * 16];                    // 4096 B

  int t = threadIdx.x;
  int l = t & 63, w = t >> 6;                       // wave w owns n in [w*64, w*64+64)
  unsigned m0 = (unsigned)blockIdx.x * 64u;

  // A path: thread t loads X[row=t>>3][4 f32 at (t&7)*4], slot-swizzled write
  int arow = t >> 3, k8 = t & 7;
  const float* Xbase = X + ((size_t)m0 + arow) * FIN + k8 * 4;
  int awoff = arow * 64 + (((k8 >> 1) ^ ((arow >> 1) & 3)) << 4) + (k8 & 1) * 8;

  // B direct-from-global fragment base: lane n-row = w*64 + ni*16 + (l&15),
  // k-chunk = kt*32 + (l>>4)*8 (16B contiguous per lane)
  const _Float16* WTb = WT + (size_t)(w * 64 + (l & 15)) * FIN + (l >> 4) * 8;

  // A fragment reads (swizzle matches awoff)
  int fsw = (((l >> 4) ^ ((l >> 1) & 3)) << 4);
  int aoff[4];
  #pragma unroll
  for (int mi = 0; mi < 4; ++mi)
    aoff[mi] = (mi * 16 + (l & 15)) * 64 + fsw;

  f32x4 zz = {0.f, 0.f, 0.f, 0.f};
  f32x4 acc[4][4];
  #pragma unroll
  for (int mi = 0; mi < 4; ++mi)
    #pragma unroll
    for (int ni = 0; ni < 4; ++ni) acc[mi][ni] = zz;

  f32x4 xv0, xv1, xv2;
  half8 bf[4];

#define K1_XLOAD(XV, KT) do {                                                  \
    int ktc_ = (KT) > 31 ? 31 : (KT);                                          \
    (XV) = *(const f32x4*)(Xbase + (size_t)ktc_ * 32);                         \
  } while (0)

#define K1_BFLOAD(KT) do {                                                     \
    _Pragma("unroll")                                                          \
    for (int ni = 0; ni < 4; ++ni)                                             \
      bf[ni] = *(const half8*)(WTb + (size_t)(ni * 16) * FIN + (KT) * 32);     \
  } while (0)

#define K1_AWRITE(NA, XV) do {                                                 \
    half4 h;                                                                   \
    h[0] = (_Float16)(XV)[0]; h[1] = (_Float16)(XV)[1];                        \
    h[2] = (_Float16)(XV)[2]; h[3] = (_Float16)(XV)[3];                        \
    *(half4*)((char*)(NA) + awoff) = h;                                        \
  } while (0)

#define K1_MFMA(CA) do {                                                       \
    half8 af[4];                                                               \
    _Pragma("unroll")                                                          \
    for (int mi = 0; mi < 4; ++mi)                                             \
      af[mi] = *(const half8*)((const char*)(CA) + aoff[mi]);                  \
    _Pragma("unroll")                                                          \
    for (int mi = 0; mi < 4; ++mi)                                             \
      _Pragma("unroll")                                                        \
      for (int ni = 0; ni < 4; ++ni)                                           \
        acc[mi][ni] = __builtin_amdgcn_mfma_f32_16x16x32_f16(                  \
            af[mi], bf[ni], acc[mi][ni], 0, 0, 0);                             \
  } while (0)

// one phase: refresh X(KT+3) into XR, compute tile KT, load B(KT+1),
// stage A(KT+1) from XW, barrier (lgkm only -- X/B stay in flight)
#define K1_PHASE(KT, XR, XW, CUR, NXT) do {                                    \
    K1_XLOAD(XR, (KT) + 3);                                                    \
    K1_MFMA(CUR);                                                              \
    K1_BFLOAD((KT) + 1);                                                       \
    K1_AWRITE(NXT, XW);                                                        \
    BAR_LGKM();                                                                \
  } while (0)

  // prologue: X0..X2 + B(0) in flight; A(0) staged
  K1_XLOAD(xv0, 0);
  K1_XLOAD(xv1, 1);
  K1_XLOAD(xv2, 2);
  K1_BFLOAD(0);
  K1_AWRITE(Al0, xv0);            // compiler waits vmcnt for xv0 only
  BAR_LGKM();

  #pragma unroll 1
  for (int kt = 0; kt < 30; kt += 6) {
    K1_PHASE(kt + 0, xv0, xv1, Al0, Al1);
    K1_PHASE(kt + 1, xv1, xv2, Al1, Al0);
    K1_PHASE(kt + 2, xv2, xv0, Al0, Al1);
    K1_PHASE(kt + 3, xv0, xv1, Al1, Al0);
    K1_PHASE(kt + 4, xv1, xv2, Al0, Al1);
    K1_PHASE(kt + 5, xv2, xv0, Al1, Al0);
  }
  K1_PHASE(30, xv0, xv1, Al0, Al1);   // loads bf(31), stages A(31)
  K1_MFMA(Al1);                        // tile 31

  // ---- fused Wh1/Wh2 = acc . a ; red[m][16] = 8 waves x {s1,s2}
  float aC1[4], aC2[4];
  #pragma unroll
  for (int ni = 0; ni < 4; ++ni) {
    int C = w * 64 + ni * 16 + (l & 15);
    aC1[ni] = av[C];
    aC2[ni] = av[FOUT + C];
  }
  float p1[4][4], p2[4][4];
  #pragma unroll
  for (int mi = 0; mi < 4; ++mi)
    #pragma unroll
    for (int r = 0; r < 4; ++r) {
      float s1 = 0.f, s2 = 0.f;
      #pragma unroll
      for (int ni = 0; ni < 4; ++ni) {
        s1 = fmaf(acc[mi][ni][r], aC1[ni], s1);
        s2 = fmaf(acc[mi][ni][r], aC2[ni], s2);
      }
      p1[mi][r] = s1; p2[mi][r] = s2;
    }
  #pragma unroll
  for (int mm = 1; mm < 16; mm <<= 1)
    #pragma unroll
    for (int mi = 0; mi < 4; ++mi)
      #pragma unroll
      for (int r = 0; r < 4; ++r) {
        p1[mi][r] += __shfl_xor(p1[mi][r], mm);
        p2[mi][r] += __shfl_xor(p2[mi][r], mm);
      }
  if ((l & 15) == 0) {
    #pragma unroll
    for (int mi = 0; mi < 4; ++mi)
      #pragma unroll
      for (int r = 0; r < 4; ++r) {
        int m = mi * 16 + (l >> 4) * 4 + r;
        red[m * 16 + w * 2]     = p1[mi][r];
        red[m * 16 + w * 2 + 1] = p2[mi][r];
      }
  }
  __syncthreads();
  if (t < 64) {
    float s1 = 0.f, s2 = 0.f;
    #pragma unroll
    for (int q = 0; q < 8; ++q) {
      s1 += red[t * 16 + q * 2];
      s2 += red[t * 16 + q * 2 + 1];
    }
    Wh1g[m0 + t] = s1;
    Wh2g[m0 + t] = s2;
  }

  // ---- direct Wh[b][f][96] stores (m-quads never straddle batches)
  #pragma unroll
  for (int mi = 0; mi < 4; ++mi) {
    unsigned mq = m0 + mi * 16 + (l >> 4) * 4;
    unsigned bb = (unsigned)(((unsigned long long)mq * 46684428ull) >> 32);
    unsigned n2 = mq - bb * 92u;
    #pragma unroll
    for (int ni = 0; ni < 4; ++ni) {
      int C = w * 64 + ni * 16 + (l & 15);
      half4 h;
      h[0] = (_Float16)acc[mi][ni][0]; h[1] = (_Float16)acc[mi][ni][1];
      h[2] = (_Float16)acc[mi][ni][2]; h[3] = (_Float16)acc[mi][ni][3];
      *(half4*)(Wh + ((size_t)bb * FOUT + C) * 96 + n2) = h;
    }
  }
}

// ---------------------------------------------------------------------------
// K2: per-batch attention. QK+softmax from LDS; PV over 8 reg-staged chunks
//     of 64 f-rows (3 rotating sets, 2 in flight), dbuf LDS, lgkm barriers.
// ---------------------------------------------------------------------------
__global__ __launch_bounds__(512, 4) void attn_kernel(
    const _Float16* __restrict__ Wh, const _Float16* __restrict__ ATp,
    const int* __restrict__ adj, const float* __restrict__ Wh1g,
    const float* __restrict__ Wh2g, const float* __restrict__ bias,
    float* __restrict__ out) {
  extern __shared__ char smem[];
  _Float16* at_  = (_Float16*)smem;                 // [96][104] 19968 B
  _Float16* e0a  = (_Float16*)(smem + 19968);       // [96][104] 19968 B
  _Float16* whc0 = (_Float16*)(smem + 39936);       // [64][104] 13312 B
  _Float16* whc1 = (_Float16*)(smem + 53248);       // [64][104] 13312 B
  float* w1s = (float*)(smem + 66560);              // [96]
  float* w2s = (float*)(smem + 66944);              // [96]

  int t = threadIdx.x, l = t & 63, w = t >> 6;
  int b = blockIdx.x;
  const _Float16* WhB = Wh + (size_t)b * FOUT * 96;

  half8 st[3][2];
  bool stager = (t < 384);
  int srow = t / 6, scol = (t - srow * 6) * 16;

#define K2_LD(S, C) do { if (stager) {                                         \
    st[S][0] = *(const half8*)(WhB + (C) * 6144 + t * 16);                     \
    st[S][1] = *(const half8*)(WhB + (C) * 6144 + t * 16 + 8); } } while (0)
#define K2_WR(BUF, S) do { if (stager) {                                       \
    *(half8*)((BUF) + srow * 104 + scol)     = st[S][0];                       \
    *(half8*)((BUF) + srow * 104 + scol + 8) = st[S][1]; } } while (0)

  K2_LD(0, 0);
  K2_LD(1, 1);

  for (int idx = t; idx < 1248; idx += 512)
    *(half8*)(at_ + idx * 8) = *(const half8*)(ATp + idx * 8);
  if (t < 96) w1s[t] = (t < 92) ? Wh1g[(size_t)b * NNODE + t] : 0.f;
  else if (t < 192) {
    int j = t - 96;
    w2s[j] = (j < 92) ? Wh2g[(size_t)b * NNODE + j] : 0.f;
  }
  BAR_LGKM();

  for (int idx = t; idx < 96 * 128; idx += 512) {
    int i = idx >> 7, k = idx & 127;
    if (k < 104) {
      float v = (i < 92 && k < 92) ? lrelu(w1s[i] + w2s[k]) : 0.f;
      e0a[i * 104 + k] = (_Float16)v;
    }
  }
  BAR_LGKM();

  if (w < 6) {
    f32x4 ez = {0.f, 0.f, 0.f, 0.f};
    f32x4 eacc[6];
    #pragma unroll
    for (int ni = 0; ni < 6; ++ni) eacc[ni] = ez;
    #pragma unroll
    for (int ks = 0; ks < 3; ++ks) {
      half8 ea = *(const half8*)((const char*)e0a +
                 (16 * w + (l & 15)) * 208 + ks * 64 + (l >> 4) * 16);
      #pragma unroll
      for (int ni = 0; ni < 6; ++ni) {
        half8 bt = *(const half8*)((const char*)at_ +
                   (16 * ni + (l & 15)) * 208 + ks * 64 + (l >> 4) * 16);
        eacc[ni] = __builtin_amdgcn_mfma_f32_16x16x32_f16(ea, bt, eacc[ni], 0, 0, 0);
      }
    }
    float attv[4][6];
    #pragma unroll
    for (int r = 0; r < 4; ++r) {
      int i = 16 * w + (l >> 4) * 4 + r;
      float s[6]; float m = -3.0e38f;
      #pragma unroll
      for (int ni = 0; ni < 6; ++ni) {
        int j = ni * 16 + (l & 15);
        float e = lrelu(eacc[ni][r]);
        float sv = -3.0e38f;
        if (i < 92 && j < 92) {
          int avj = adj[((size_t)b * NNODE + i) * NNODE + j];
          sv = (avj > 0) ? e : -9.0e15f;
        }
        s[ni] = sv;
        m = fmaxf(m, sv);
      }
      #pragma unroll
      for (int mm = 1; mm < 16; mm <<= 1) m = fmaxf(m, __shfl_xor(m, mm));
      float sum = 0.f; float p[6];
      #pragma unroll
      for (int ni = 0; ni < 6; ++ni) {
        int j = ni * 16 + (l & 15);
        p[ni] = (i < 92 && j < 92) ? __expf(s[ni] - m) : 0.f;
        sum += p[ni];
      }
      #pragma unroll
      for (int mm = 1; mm < 16; mm <<= 1) sum += __shfl_xor(sum, mm);
      float rs = (i < 92) ? (1.0f / sum) : 0.f;
      #pragma unroll
      for (int ni = 0; ni < 6; ++ni) attv[r][ni] = p[ni] * rs;
    }
    #pragma unroll
    for (int r = 0; r < 4; ++r) {
      int i = 16 * w + (l >> 4) * 4 + r;
      #pragma unroll
      for (int ni = 0; ni < 6; ++ni)
        e0a[i * 104 + ni * 16 + (l & 15)] = (_Float16)attv[r][ni];
    }
  }
  BAR_LGKM();

  K2_WR(whc0, 0);
  BAR_LGKM();

  int ih = w >> 2, fq = w & 3;
  #pragma unroll
  for (int c = 0; c < 8; ++c) {
    _Float16* cur = (c & 1) ? whc1 : whc0;
    _Float16* nxt = (c & 1) ? whc0 : whc1;
    if (c + 1 < 8) K2_WR(nxt, (c + 1) % 3);
    if (c + 2 < 8) K2_LD((c + 2) % 3, c + 2);
    f32x4 pz = {0.f, 0.f, 0.f, 0.f};
    f32x4 pacc[3];
    pacc[0] = pz; pacc[1] = pz; pacc[2] = pz;
    #pragma unroll
    for (int ks = 0; ks < 3; ++ks) {
      half8 bf = *(const half8*)((const char*)cur +
                 (fq * 16 + (l & 15)) * 208 + ks * 64 + (l >> 4) * 16);
      #pragma unroll
      for (int q = 0; q < 3; ++q) {
        half8 af = *(const half8*)((const char*)e0a +
                   (16 * (ih * 3 + q) + (l & 15)) * 208 + ks * 64 + (l >> 4) * 16);
        pacc[q] = __builtin_amdgcn_mfma_f32_16x16x32_f16(af, bf, pacc[q], 0, 0, 0);
      }
    }
    int fcol = c * 64 + fq * 16 + (l & 15);
    float bv = bias[fcol];
    #pragma unroll
    for (int q = 0; q < 3; ++q)
      #pragma unroll
      for (int r = 0; r < 4; ++r) {
        int i = 16 * (ih * 3 + q) + (l >> 4) * 4 + r;
        if (i < 92)
          out[((size_t)b * NNODE + i) * FOUT + fcol] = pacc[q][r] + bv;
      }
    if (c + 1 < 8) BAR_LGKM();
  }
}

// ---------------------------------------------------------------------------
extern "C" void kernel_launch(void* const* d_in, const int* in_sizes, int n_in,
                              void* d_out, int out_size, void* d_ws, size_t ws_size,
                              hipStream_t stream) {
  (void)in_sizes; (void)n_in; (void)out_size; (void)ws_size;
  const float* X    = (const float*)d_in[0];
  const int*   adj  = (const int*)d_in[1];
  const float* W    = (const float*)d_in[2];
  const float* av   = (const float*)d_in[3];
  const float* Am   = (const float*)d_in[4];
  const float* bias = (const float*)d_in[5];
  float* out = (float*)d_out;
  char* ws = (char*)d_ws;

  _Float16* WT  = (_Float16*)(ws);              // 1,048,576 B
  _Float16* ATp = (_Float16*)(ws + 1048576);    //    19,968 B
  float* Wh1 = (float*)(ws + 1068544);          //   376,832 B
  float* Wh2 = (float*)(ws + 1445376);          //   376,832 B
  _Float16* Wh = (_Float16*)(ws + 1822208);     // 100,663,296 B  [b][f][96]

  prep_kernel<<<68, 256, 0, stream>>>(W, Am, WT, ATp);
  gemm_kernel<<<1472, 512, 0, stream>>>(X, WT, av, Wh, Wh1, Wh2);
  hipFuncSetAttribute((const void*)attn_kernel,
                      hipFuncAttributeMaxDynamicSharedMemorySize, 67584);
  attn_kernel<<<1024, 512, 67584, stream>>>(Wh, ATp, adj, Wh1, Wh2, bias, out);
}

// Round 10
// 418.841 us; speedup vs baseline: 1.0081x; 1.0081x over previous
//
#include <hip/hip_runtime.h>

#define BATCH 1024
#define NNODE 92
#define FIN   1024
#define FOUT  512

typedef float    f32x4 __attribute__((ext_vector_type(4)));
typedef _Float16 half8 __attribute__((ext_vector_type(8)));
typedef _Float16 half4 __attribute__((ext_vector_type(4)));

__device__ __forceinline__ float lrelu(float x) { return fmaxf(x, 0.2f * x); }

#define BAR_LGKM() do {                                                        \
    asm volatile("s_waitcnt lgkmcnt(0)" ::: "memory");                         \
    __builtin_amdgcn_sched_barrier(0);                                         \
    __builtin_amdgcn_s_barrier();                                              \
  } while (0)

// ---------------------------------------------------------------------------
// prep: WT[n][k] = f16(W[k][n]);  ATp[j][k] = f16(A[k][j]) padded [96][104]
// ---------------------------------------------------------------------------
__global__ __launch_bounds__(256) void prep_kernel(
    const float* __restrict__ W, const float* __restrict__ Am,
    _Float16* __restrict__ WT, _Float16* __restrict__ ATp) {
  int bid = blockIdx.x, t = threadIdx.x;
  if (bid < 64) {
    int n0 = bid * 8;
    for (int it = 0; it < 4; ++it) {
      int k = it * 256 + t;
      const f32x4* src = (const f32x4*)(W + (size_t)k * FOUT + n0);
      f32x4 v0 = src[0], v1 = src[1];
      #pragma unroll
      for (int c = 0; c < 4; ++c) {
        WT[(size_t)(n0 + c) * FIN + k]     = (_Float16)v0[c];
        WT[(size_t)(n0 + 4 + c) * FIN + k] = (_Float16)v1[c];
      }
    }
  } else {
    int j0 = (bid - 64) * 24;
    for (int idx = t; idx < 24 * 104; idx += 256) {
      int jr = idx / 104, k = idx - jr * 104;
      int j = j0 + jr;
      float v = (j < NNODE && k < NNODE) ? Am[k * NNODE + j] : 0.f;
      ATp[j * 104 + k] = (_Float16)v;
    }
  }
}

// ---------------------------------------------------------------------------
// K1: Wh = X @ W. 1472 blocks x 512 thr, tile 64m x 512n (X read once).
//     8 waves, each 64m x 64n. BK=128 -> only 8 barrier phases. Within a
//     phase: 4 k-subphases of 32 with register-double-buffered B fragments
//     loaded global->reg from L2-hot WT (no barriers between subphases).
//     A tile [64][128] f16 in LDS (16 KB dbuf), slot^=(row&7) swizzle.
//     X prefetch (4 x f32x4/thread) issued at phase start, lands under MFMA.
//     Epilogue: fused Wh1/Wh2 + coalesced tbuf transpose stores (R5-style).
// ---------------------------------------------------------------------------
__global__ __launch_bounds__(512, 3) void gemm_kernel(
    const float* __restrict__ X, const _Float16* __restrict__ WT,
    const float* __restrict__ av, _Float16* __restrict__ Wh,
    float* __restrict__ Wh1g, float* __restrict__ Wh2g) {
  extern __shared__ char smem[];
  _Float16* Al0 = (_Float16*)smem;              // [64][128] f16 swz, 16384 B
  _Float16* Al1 = (_Float16*)(smem + 16384);
  _Float16* tbuf = (_Float16*)smem;             // [64][513] f16, 65664 B
  float* red = (float*)(smem + 65664);          // [64][16] f32, 4096 B

  int t = threadIdx.x;
  int l = t & 63, w = t >> 6;                   // wave w owns n [w*64, w*64+64)
  unsigned m0 = (unsigned)blockIdx.x * 64u;

  // X path: thread t covers row t>>3, 16 consecutive f32 at col (t&7)*16
  int arow = t >> 3, k16 = t & 7;
  const float* Xbase = X + ((size_t)m0 + arow) * FIN + k16 * 16;
  // A LDS write offsets: for q=0..3, kbyte = k16*32 + q*8,
  // slot = kbyte>>4 ^ (row&7), within = (q&1)*8
  int awoff[4];
  #pragma unroll
  for (int q = 0; q < 4; ++q) {
    int slot = (k16 * 2 + (q >> 1)) ^ (arow & 7);
    awoff[q] = arow * 256 + (slot << 4) + (q & 1) * 8;
  }

  // B direct-from-global: lane n-row = w*64 + ni*16 + (l&15), 16B at k-chunk
  const _Float16* WTb = WT + (size_t)(w * 64 + (l & 15)) * FIN + (l >> 4) * 8;

  // A fragment read offsets per (mi, ks): row = mi*16+(l&15),
  // slot = ks*4 + (l>>4) ^ (row&7)
  int afrow[4];
  #pragma unroll
  for (int mi = 0; mi < 4; ++mi) afrow[mi] = mi * 16 + (l & 15);

  f32x4 zz = {0.f, 0.f, 0.f, 0.f};
  f32x4 acc[4][4];
  #pragma unroll
  for (int mi = 0; mi < 4; ++mi)
    #pragma unroll
    for (int ni = 0; ni < 4; ++ni) acc[mi][ni] = zz;

  f32x4 xv0, xv1, xv2, xv3;
  half8 bfA[4], bfB[4];

#define K1_XLOAD(XV, KT, Q) do {                                               \
    int ktc_ = (KT) > 7 ? 7 : (KT);                                            \
    (XV) = *(const f32x4*)(Xbase + (size_t)ktc_ * 128 + (Q) * 4);              \
  } while (0)

#define K1_BFLOAD(DST, KT, KS) do {                                            \
    int ktc_ = (KT) > 7 ? 7 : (KT);                                            \
    _Pragma("unroll")                                                          \
    for (int ni = 0; ni < 4; ++ni)                                             \
      (DST)[ni] = *(const half8*)(WTb + (size_t)(ni * 16) * FIN +              \
                                  ktc_ * 128 + (KS) * 32);                     \
  } while (0)

#define K1_AWRITE(NA) do {                                                     \
    half4 h0, h1, h2, h3;                                                      \
    h0[0]=(_Float16)xv0[0]; h0[1]=(_Float16)xv0[1];                            \
    h0[2]=(_Float16)xv0[2]; h0[3]=(_Float16)xv0[3];                            \
    h1[0]=(_Float16)xv1[0]; h1[1]=(_Float16)xv1[1];                            \
    h1[2]=(_Float16)xv1[2]; h1[3]=(_Float16)xv1[3];                            \
    h2[0]=(_Float16)xv2[0]; h2[1]=(_Float16)xv2[1];                            \
    h2[2]=(_Float16)xv2[2]; h2[3]=(_Float16)xv2[3];                            \
    h3[0]=(_Float16)xv3[0]; h3[1]=(_Float16)xv3[1];                            \
    h3[2]=(_Float16)xv3[2]; h3[3]=(_Float16)xv3[3];                            \
    *(half4*)((char*)(NA) + awoff[0]) = h0;                                    \
    *(half4*)((char*)(NA) + awoff[1]) = h1;                                    \
    *(half4*)((char*)(NA) + awoff[2]) = h2;                                    \
    *(half4*)((char*)(NA) + awoff[3]) = h3;                                    \
  } while (0)

#define K1_MFMA_KS(CA, BF, KS) do {                                            \
    half8 af[4];                                                               \
    _Pragma("unroll")                                                          \
    for (int mi = 0; mi < 4; ++mi) {                                           \
      int slot_ = ((KS) * 4 + (l >> 4)) ^ (afrow[mi] & 7);                     \
      af[mi] = *(const half8*)((const char*)(CA) + afrow[mi] * 256 +           \
                               (slot_ << 4));                                  \
    }                                                                          \
    _Pragma("unroll")                                                          \
    for (int mi = 0; mi < 4; ++mi)                                             \
      _Pragma("unroll")                                                        \
      for (int ni = 0; ni < 4; ++ni)                                           \
        acc[mi][ni] = __builtin_amdgcn_mfma_f32_16x16x32_f16(                  \
            af[mi], (BF)[ni], acc[mi][ni], 0, 0, 0);                           \
  } while (0)

// one BK=128 phase: compute phase KT from CUR, stage phase KT+1 into NXT
#define K1_PHASE(KT, CUR, NXT) do {                                            \
    K1_XLOAD(xv0, (KT) + 1, 0);                                                \
    K1_XLOAD(xv1, (KT) + 1, 1);                                                \
    K1_BFLOAD(bfB, (KT), 1);                                                   \
    K1_MFMA_KS(CUR, bfA, 0);                                                   \
    K1_XLOAD(xv2, (KT) + 1, 2);                                                \
    K1_XLOAD(xv3, (KT) + 1, 3);                                                \
    K1_BFLOAD(bfA, (KT), 2);                                                   \
    K1_MFMA_KS(CUR, bfB, 1);                                                   \
    K1_BFLOAD(bfB, (KT), 3);                                                   \
    K1_MFMA_KS(CUR, bfA, 2);                                                   \
    K1_BFLOAD(bfA, (KT) + 1, 0);                                               \
    K1_MFMA_KS(CUR, bfB, 3);                                                   \
    K1_AWRITE(NXT);                                                            \
    BAR_LGKM();                                                                \
  } while (0)

  // prologue: stage A(0), load bfA(0, ks=0)
  K1_XLOAD(xv0, 0, 0);
  K1_XLOAD(xv1, 0, 1);
  K1_XLOAD(xv2, 0, 2);
  K1_XLOAD(xv3, 0, 3);
  K1_BFLOAD(bfA, 0, 0);
  K1_AWRITE(Al0);                 // compiler waits vmcnt for xv0..3
  BAR_LGKM();

  #pragma unroll 1
  for (int kt = 0; kt < 8; kt += 2) {
    K1_PHASE(kt + 0, Al0, Al1);
    K1_PHASE(kt + 1, Al1, Al0);
  }

  // ---- fused Wh1/Wh2 = acc . a ; red[m][16] = 8 waves x {s1,s2}
  float aC1[4], aC2[4];
  #pragma unroll
  for (int ni = 0; ni < 4; ++ni) {
    int C = w * 64 + ni * 16 + (l & 15);
    aC1[ni] = av[C];
    aC2[ni] = av[FOUT + C];
  }
  float p1[4][4], p2[4][4];
  #pragma unroll
  for (int mi = 0; mi < 4; ++mi)
    #pragma unroll
    for (int r = 0; r < 4; ++r) {
      float s1 = 0.f, s2 = 0.f;
      #pragma unroll
      for (int ni = 0; ni < 4; ++ni) {
        s1 = fmaf(acc[mi][ni][r], aC1[ni], s1);
        s2 = fmaf(acc[mi][ni][r], aC2[ni], s2);
      }
      p1[mi][r] = s1; p2[mi][r] = s2;
    }
  #pragma unroll
  for (int mm = 1; mm < 16; mm <<= 1)
    #pragma unroll
    for (int mi = 0; mi < 4; ++mi)
      #pragma unroll
      for (int r = 0; r < 4; ++r) {
        p1[mi][r] += __shfl_xor(p1[mi][r], mm);
        p2[mi][r] += __shfl_xor(p2[mi][r], mm);
      }
  if ((l & 15) == 0) {
    #pragma unroll
    for (int mi = 0; mi < 4; ++mi)
      #pragma unroll
      for (int r = 0; r < 4; ++r) {
        int m = mi * 16 + (l >> 4) * 4 + r;
        red[m * 16 + w * 2]     = p1[mi][r];
        red[m * 16 + w * 2 + 1] = p2[mi][r];
      }
  }
  __syncthreads();
  if (t < 64) {
    float s1 = 0.f, s2 = 0.f;
    #pragma unroll
    for (int q = 0; q < 8; ++q) {
      s1 += red[t * 16 + q * 2];
      s2 += red[t * 16 + q * 2 + 1];
    }
    Wh1g[m0 + t] = s1;
    Wh2g[m0 + t] = s2;
  }

  // ---- dump acc -> tbuf m-major [64][513] (red not aliased: offset 65664)
  #pragma unroll
  for (int mi = 0; mi < 4; ++mi)
    #pragma unroll
    for (int ni = 0; ni < 4; ++ni) {
      int C = w * 64 + ni * 16 + (l & 15);
      #pragma unroll
      for (int r = 0; r < 4; ++r) {
        int m = mi * 16 + (l >> 4) * 4 + r;
        tbuf[m * 513 + C] = (_Float16)acc[mi][ni][r];
      }
    }
  __syncthreads();

  // ---- coalesced stores: thread t owns column C=t of Wh[b][f][96]
  {
    unsigned mEnd = m0 + 64u;
    unsigned b0 = m0 / 92u;
    #pragma unroll 1
    for (unsigned seg = 0; seg < 2; ++seg) {
      unsigned bbase = b0 + seg;
      unsigned bstart = bbase * 92u;
      if (bstart >= mEnd) break;
      unsigned s = (bstart < m0) ? (m0 - bstart) : 0u;
      unsigned e = (mEnd - bstart < 92u) ? (mEnd - bstart) : 92u;
      if (s >= e) continue;
      _Float16* gp = Wh + ((size_t)bbase * FOUT + t) * 96;
      for (unsigned m8 = s & ~7u; m8 < e; m8 += 8) {
        unsigned lo = (m8 < s) ? s : m8;
        unsigned hi = (m8 + 8 > e) ? e : m8 + 8;
        if (hi - lo == 8) {
          half8 v;
          #pragma unroll
          for (int q = 0; q < 8; ++q)
            v[q] = tbuf[(bstart + lo - m0 + q) * 513 + t];
          *(half8*)(gp + lo) = v;
        } else {
          for (unsigned m = lo; m < hi; ++m)
            gp[m] = tbuf[(bstart + m - m0) * 513 + t];
        }
      }
    }
  }
}

// ---------------------------------------------------------------------------
// K2: per-batch attention. QK+softmax from LDS; PV over 8 reg-staged chunks
//     of 64 f-rows (3 rotating sets, 2 in flight), dbuf LDS, lgkm barriers.
// ---------------------------------------------------------------------------
__global__ __launch_bounds__(512, 4) void attn_kernel(
    const _Float16* __restrict__ Wh, const _Float16* __restrict__ ATp,
    const int* __restrict__ adj, const float* __restrict__ Wh1g,
    const float* __restrict__ Wh2g, const float* __restrict__ bias,
    float* __restrict__ out) {
  extern __shared__ char smem[];
  _Float16* at_  = (_Float16*)smem;                 // [96][104] 19968 B
  _Float16* e0a  = (_Float16*)(smem + 19968);       // [96][104] 19968 B
  _Float16* whc0 = (_Float16*)(smem + 39936);       // [64][104] 13312 B
  _Float16* whc1 = (_Float16*)(smem + 53248);       // [64][104] 13312 B
  float* w1s = (float*)(smem + 66560);              // [96]
  float* w2s = (float*)(smem + 66944);              // [96]

  int t = threadIdx.x, l = t & 63, w = t >> 6;
  int b = blockIdx.x;
  const _Float16* WhB = Wh + (size_t)b * FOUT * 96;

  half8 st[3][2];
  bool stager = (t < 384);
  int srow = t / 6, scol = (t - srow * 6) * 16;

#define K2_LD(S, C) do { if (stager) {                                         \
    st[S][0] = *(const half8*)(WhB + (C) * 6144 + t * 16);                     \
    st[S][1] = *(const half8*)(WhB + (C) * 6144 + t * 16 + 8); } } while (0)
#define K2_WR(BUF, S) do { if (stager) {                                       \
    *(half8*)((BUF) + srow * 104 + scol)     = st[S][0];                       \
    *(half8*)((BUF) + srow * 104 + scol + 8) = st[S][1]; } } while (0)

  K2_LD(0, 0);
  K2_LD(1, 1);

  for (int idx = t; idx < 1248; idx += 512)
    *(half8*)(at_ + idx * 8) = *(const half8*)(ATp + idx * 8);
  if (t < 96) w1s[t] = (t < 92) ? Wh1g[(size_t)b * NNODE + t] : 0.f;
  else if (t < 192) {
    int j = t - 96;
    w2s[j] = (j < 92) ? Wh2g[(size_t)b * NNODE + j] : 0.f;
  }
  BAR_LGKM();

  for (int idx = t; idx < 96 * 128; idx += 512) {
    int i = idx >> 7, k = idx & 127;
    if (k < 104) {
      float v = (i < 92 && k < 92) ? lrelu(w1s[i] + w2s[k]) : 0.f;
      e0a[i * 104 + k] = (_Float16)v;
    }
  }
  BAR_LGKM();

  if (w < 6) {
    f32x4 ez = {0.f, 0.f, 0.f, 0.f};
    f32x4 eacc[6];
    #pragma unroll
    for (int ni = 0; ni < 6; ++ni) eacc[ni] = ez;
    #pragma unroll
    for (int ks = 0; ks < 3; ++ks) {
      half8 ea = *(const half8*)((const char*)e0a +
                 (16 * w + (l & 15)) * 208 + ks * 64 + (l >> 4) * 16);
      #pragma unroll
      for (int ni = 0; ni < 6; ++ni) {
        half8 bt = *(const half8*)((const char*)at_ +
                   (16 * ni + (l & 15)) * 208 + ks * 64 + (l >> 4) * 16);
        eacc[ni] = __builtin_amdgcn_mfma_f32_16x16x32_f16(ea, bt, eacc[ni], 0, 0, 0);
      }
    }
    float attv[4][6];
    #pragma unroll
    for (int r = 0; r < 4; ++r) {
      int i = 16 * w + (l >> 4) * 4 + r;
      float s[6]; float m = -3.0e38f;
      #pragma unroll
      for (int ni = 0; ni < 6; ++ni) {
        int j = ni * 16 + (l & 15);
        float e = lrelu(eacc[ni][r]);
        float sv = -3.0e38f;
        if (i < 92 && j < 92) {
          int avj = adj[((size_t)b * NNODE + i) * NNODE + j];
          sv = (avj > 0) ? e : -9.0e15f;
        }
        s[ni] = sv;
        m = fmaxf(m, sv);
      }
      #pragma unroll
      for (int mm = 1; mm < 16; mm <<= 1) m = fmaxf(m, __shfl_xor(m, mm));
      float sum = 0.f; float p[6];
      #pragma unroll
      for (int ni = 0; ni < 6; ++ni) {
        int j = ni * 16 + (l & 15);
        p[ni] = (i < 92 && j < 92) ? __expf(s[ni] - m) : 0.f;
        sum += p[ni];
      }
      #pragma unroll
      for (int mm = 1; mm < 16; mm <<= 1) sum += __shfl_xor(sum, mm);
      float rs = (i < 92) ? (1.0f / sum) : 0.f;
      #pragma unroll
      for (int ni = 0; ni < 6; ++ni) attv[r][ni] = p[ni] * rs;
    }
    #pragma unroll
    for (int r = 0; r < 4; ++r) {
      int i = 16 * w + (l >> 4) * 4 + r;
      #pragma unroll
      for (int ni = 0; ni < 6; ++ni)
        e0a[i * 104 + ni * 16 + (l & 15)] = (_Float16)attv[r][ni];
    }
  }
  BAR_LGKM();

  K2_WR(whc0, 0);
  BAR_LGKM();

  int ih = w >> 2, fq = w & 3;
  #pragma unroll
  for (int c = 0; c < 8; ++c) {
    _Float16* cur = (c & 1) ? whc1 : whc0;
    _Float16* nxt = (c & 1) ? whc0 : whc1;
    if (c + 1 < 8) K2_WR(nxt, (c + 1) % 3);
    if (c + 2 < 8) K2_LD((c + 2) % 3, c + 2);
    f32x4 pz = {0.f, 0.f, 0.f, 0.f};
    f32x4 pacc[3];
    pacc[0] = pz; pacc[1] = pz; pacc[2] = pz;
    #pragma unroll
    for (int ks = 0; ks < 3; ++ks) {
      half8 bf = *(const half8*)((const char*)cur +
                 (fq * 16 + (l & 15)) * 208 + ks * 64 + (l >> 4) * 16);
      #pragma unroll
      for (int q = 0; q < 3; ++q) {
        half8 af = *(const half8*)((const char*)e0a +
                   (16 * (ih * 3 + q) + (l & 15)) * 208 + ks * 64 + (l >> 4) * 16);
        pacc[q] = __builtin_amdgcn_mfma_f32_16x16x32_f16(af, bf, pacc[q], 0, 0, 0);
      }
    }
    int fcol = c * 64 + fq * 16 + (l & 15);
    float bv = bias[fcol];
    #pragma unroll
    for (int q = 0; q < 3; ++q)
      #pragma unroll
      for (int r = 0; r < 4; ++r) {
        int i = 16 * (ih * 3 + q) + (l >> 4) * 4 + r;
        if (i < 92)
          out[((size_t)b * NNODE + i) * FOUT + fcol] = pacc[q][r] + bv;
      }
    if (c + 1 < 8) BAR_LGKM();
  }
}

// ---------------------------------------------------------------------------
extern "C" void kernel_launch(void* const* d_in, const int* in_sizes, int n_in,
                              void* d_out, int out_size, void* d_ws, size_t ws_size,
                              hipStream_t stream) {
  (void)in_sizes; (void)n_in; (void)out_size; (void)ws_size;
  const float* X    = (const float*)d_in[0];
  const int*   adj  = (const int*)d_in[1];
  const float* W    = (const float*)d_in[2];
  const float* av   = (const float*)d_in[3];
  const float* Am   = (const float*)d_in[4];
  const float* bias = (const float*)d_in[5];
  float* out = (float*)d_out;
  char* ws = (char*)d_ws;

  _Float16* WT  = (_Float16*)(ws);              // 1,048,576 B
  _Float16* ATp = (_Float16*)(ws + 1048576);    //    19,968 B
  float* Wh1 = (float*)(ws + 1068544);          //   376,832 B
  float* Wh2 = (float*)(ws + 1445376);          //   376,832 B
  _Float16* Wh = (_Float16*)(ws + 1822208);     // 100,663,296 B  [b][f][96]

  prep_kernel<<<68, 256, 0, stream>>>(W, Am, WT, ATp);
  hipFuncSetAttribute((const void*)gemm_kernel,
                      hipFuncAttributeMaxDynamicSharedMemorySize, 69760);
  gemm_kernel<<<1472, 512, 69760, stream>>>(X, WT, av, Wh, Wh1, Wh2);
  hipFuncSetAttribute((const void*)attn_kernel,
                      hipFuncAttributeMaxDynamicSharedMemorySize, 67584);
  attn_kernel<<<1024, 512, 67584, stream>>>(Wh, ATp, adj, Wh1, Wh2, bias, out);
}

// Round 11
// 312.433 us; speedup vs baseline: 1.3514x; 1.3406x over previous
//
#include <hip/hip_runtime.h>

#define BATCH 1024
#define NNODE 92
#define FIN   1024
#define FOUT  512

typedef float    f32x4 __attribute__((ext_vector_type(4)));
typedef _Float16 half8 __attribute__((ext_vector_type(8)));
typedef _Float16 half4 __attribute__((ext_vector_type(4)));

__device__ __forceinline__ float lrelu(float x) { return fmaxf(x, 0.2f * x); }

#define BAR_LGKM() do {                                                        \
    asm volatile("s_waitcnt lgkmcnt(0)" ::: "memory");                         \
    __builtin_amdgcn_sched_barrier(0);                                         \
    __builtin_amdgcn_s_barrier();                                              \
  } while (0)

// ---------------------------------------------------------------------------
// prep: WT[n][k] = f16(W[k][n]);  ATp[j][k] = f16(A[k][j]) padded [96][104]
// ---------------------------------------------------------------------------
__global__ __launch_bounds__(256) void prep_kernel(
    const float* __restrict__ W, const float* __restrict__ Am,
    _Float16* __restrict__ WT, _Float16* __restrict__ ATp) {
  int bid = blockIdx.x, t = threadIdx.x;
  if (bid < 64) {
    int n0 = bid * 8;
    for (int it = 0; it < 4; ++it) {
      int k = it * 256 + t;
      const f32x4* src = (const f32x4*)(W + (size_t)k * FOUT + n0);
      f32x4 v0 = src[0], v1 = src[1];
      #pragma unroll
      for (int c = 0; c < 4; ++c) {
        WT[(size_t)(n0 + c) * FIN + k]     = (_Float16)v0[c];
        WT[(size_t)(n0 + 4 + c) * FIN + k] = (_Float16)v1[c];
      }
    }
  } else {
    int j0 = (bid - 64) * 24;
    for (int idx = t; idx < 24 * 104; idx += 256) {
      int jr = idx / 104, k = idx - jr * 104;
      int j = j0 + jr;
      float v = (j < NNODE && k < NNODE) ? Am[k * NNODE + j] : 0.f;
      ATp[j * 104 + k] = (_Float16)v;
    }
  }
}

// ---------------------------------------------------------------------------
// FUSED: one block per batch (1024 x 512 thr, 154 KB LDS, 1 block/CU).
//  Phase A (GEMM): Wh[b] = X[b] @ W into LDS whT[512 f][104 m] f16.
//    16 phases of BK=64; X chunk [96][64] f16 staged dbuf (swizzled,
//    2-phase-deep register prefetch); B frags global->reg from L2-hot WT;
//    8 waves, wave = 96m x 64n (acc[6][4]); barrier = lgkmcnt(0) only.
//  Phase B (attention): Wh1/Wh2 from acc (fused reduction), at_ staged
//    into the dead X-stage LDS, e0 -> QK MFMA -> softmax -> att -> PV
//    from whT -> out. Verbatim-adapted from the passing K2.
// LDS map (bytes): whT 0..106495 | xs0 106496 | xs1 118784 (at_ overlays
// 106496 after GEMM) | e0a 131072 | red 151040 | w1s 157184 | w2s 157568.
// ---------------------------------------------------------------------------
__global__ __launch_bounds__(512, 2) void fused_kernel(
    const float* __restrict__ X, const _Float16* __restrict__ WT,
    const _Float16* __restrict__ ATp, const int* __restrict__ adj,
    const float* __restrict__ av, const float* __restrict__ bias,
    float* __restrict__ out) {
  extern __shared__ char smem[];
  _Float16* whT = (_Float16*)smem;                  // [512][104]
  _Float16* xs0 = (_Float16*)(smem + 106496);       // [96][64] swz
  _Float16* xs1 = (_Float16*)(smem + 118784);
  _Float16* at_ = (_Float16*)(smem + 106496);       // overlays xs after GEMM
  _Float16* e0a = (_Float16*)(smem + 131072);       // [96][104]
  float* red = (float*)(smem + 151040);             // [96][16]
  float* w1s = (float*)(smem + 157184);             // [96]
  float* w2s = (float*)(smem + 157568);             // [96]

  int t = threadIdx.x, l = t & 63, w = t >> 6;
  int b = blockIdx.x;
  const float* Xb = X + (size_t)b * NNODE * FIN;

  // ---- X staging maps: idx = c*512+t, row = idx>>4 (0..95), kq = idx&15
  int xrow[3], xwoff[3];
  bool xok[3];
  #pragma unroll
  for (int c = 0; c < 3; ++c) {
    int idx = c * 512 + t;
    int row = idx >> 4, kq = idx & 15;
    xrow[c] = (row < 92) ? row : 91;
    xok[c] = (row < 92);
    xwoff[c] = row * 128 + (((kq >> 1) ^ (row & 7)) << 4) + (kq & 1) * 8;
  }

  // ---- B direct-from-global fragment base
  const _Float16* WTb = WT + (size_t)(w * 64 + (l & 15)) * FIN + (l >> 4) * 8;

  f32x4 zz = {0.f, 0.f, 0.f, 0.f};
  f32x4 acc[6][4];
  #pragma unroll
  for (int mi = 0; mi < 6; ++mi)
    #pragma unroll
    for (int ni = 0; ni < 4; ++ni) acc[mi][ni] = zz;

  f32x4 xvA[3], xvB[3];
  half8 bfA[4], bfB[4];

#define F_XISSUE(XV, KT) do {                                                  \
    int ktc_ = (KT) > 15 ? 15 : (KT);                                          \
    _Pragma("unroll")                                                          \
    for (int c = 0; c < 3; ++c) {                                              \
      int idx_ = c * 512 + t;                                                  \
      (XV)[c] = *(const f32x4*)(Xb + (size_t)xrow[c] * FIN + ktc_ * 64 +       \
                                (idx_ & 15) * 4);                              \
    }                                                                          \
  } while (0)

#define F_XCONV(BUF, XV) do {                                                  \
    _Pragma("unroll")                                                          \
    for (int c = 0; c < 3; ++c) {                                              \
      half4 h;                                                                 \
      if (xok[c]) {                                                            \
        h[0] = (_Float16)(XV)[c][0]; h[1] = (_Float16)(XV)[c][1];              \
        h[2] = (_Float16)(XV)[c][2]; h[3] = (_Float16)(XV)[c][3];              \
      } else {                                                                 \
        h[0] = (_Float16)0.f; h[1] = (_Float16)0.f;                            \
        h[2] = (_Float16)0.f; h[3] = (_Float16)0.f;                            \
      }                                                                        \
      *(half4*)((char*)(BUF) + xwoff[c]) = h;                                  \
    }                                                                          \
  } while (0)

#define F_BFLOAD(DST, KT, S) do {                                              \
    int ktc_ = (KT) > 15 ? 15 : (KT);                                          \
    _Pragma("unroll")                                                          \
    for (int ni = 0; ni < 4; ++ni)                                             \
      (DST)[ni] = *(const half8*)(WTb + (size_t)(ni * 16) * FIN +              \
                                  ktc_ * 64 + (S) * 32);                       \
  } while (0)

#define F_MFMA(XSBUF, BF, S) do {                                              \
    half8 af[6];                                                               \
    _Pragma("unroll")                                                          \
    for (int mi = 0; mi < 6; ++mi) {                                           \
      int row_ = mi * 16 + (l & 15);                                           \
      int slot_ = (((S) * 4 + (l >> 4)) ^ (row_ & 7));                         \
      af[mi] = *(const half8*)((const char*)(XSBUF) + row_ * 128 +             \
                               slot_ * 16);                                    \
    }                                                                          \
    _Pragma("unroll")                                                          \
    for (int mi = 0; mi < 6; ++mi)                                             \
      _Pragma("unroll")                                                        \
      for (int ni = 0; ni < 4; ++ni)                                           \
        acc[mi][ni] = __builtin_amdgcn_mfma_f32_16x16x32_f16(                  \
            af[mi], (BF)[ni], acc[mi][ni], 0, 0, 0);                           \
  } while (0)

// phase KT: compute tile KT from CUR, X(KT+2) issued, X(KT+1) converted->NXT
#define F_PHASE(KT, XN, XP, CUR, NXT) do {                                     \
    F_XISSUE(XN, (KT) + 2);                                                    \
    F_BFLOAD(bfB, (KT), 1);                                                    \
    F_MFMA(CUR, bfA, 0);                                                       \
    F_BFLOAD(bfA, (KT) + 1, 0);                                                \
    F_MFMA(CUR, bfB, 1);                                                       \
    F_XCONV(NXT, XP);                                                          \
    BAR_LGKM();                                                                \
  } while (0)

  // prologue: stage X(0), X(1) in flight, bfA(0,0)
  F_XISSUE(xvA, 0);
  F_XCONV(xs0, xvA);              // compiler waits vmcnt for xvA
  F_XISSUE(xvA, 1);
  F_BFLOAD(bfA, 0, 0);
  BAR_LGKM();

  #pragma unroll 1
  for (int kt = 0; kt < 16; kt += 2) {
    F_PHASE(kt + 0, xvB, xvA, xs0, xs1);
    F_PHASE(kt + 1, xvA, xvB, xs1, xs0);
  }

  // ---- whT write: acc -> whT[C][m] (half4, m-quads aligned)
  #pragma unroll
  for (int mi = 0; mi < 6; ++mi) {
    int m4 = mi * 16 + (l >> 4) * 4;
    #pragma unroll
    for (int ni = 0; ni < 4; ++ni) {
      int C = w * 64 + ni * 16 + (l & 15);
      half4 h;
      h[0] = (_Float16)acc[mi][ni][0]; h[1] = (_Float16)acc[mi][ni][1];
      h[2] = (_Float16)acc[mi][ni][2]; h[3] = (_Float16)acc[mi][ni][3];
      *(half4*)((char*)whT + C * 208 + m4 * 2) = h;
    }
  }

  // ---- Wh1/Wh2 = acc . a : per-lane over owned C, shfl-reduce, red[96][16]
  {
    float aC1[4], aC2[4];
    #pragma unroll
    for (int ni = 0; ni < 4; ++ni) {
      int C = w * 64 + ni * 16 + (l & 15);
      aC1[ni] = av[C];
      aC2[ni] = av[FOUT + C];
    }
    float p1[6][4], p2[6][4];
    #pragma unroll
    for (int mi = 0; mi < 6; ++mi)
      #pragma unroll
      for (int r = 0; r < 4; ++r) {
        float s1 = 0.f, s2 = 0.f;
        #pragma unroll
        for (int ni = 0; ni < 4; ++ni) {
          s1 = fmaf(acc[mi][ni][r], aC1[ni], s1);
          s2 = fmaf(acc[mi][ni][r], aC2[ni], s2);
        }
        p1[mi][r] = s1; p2[mi][r] = s2;
      }
    #pragma unroll
    for (int mm = 1; mm < 16; mm <<= 1)
      #pragma unroll
      for (int mi = 0; mi < 6; ++mi)
        #pragma unroll
        for (int r = 0; r < 4; ++r) {
          p1[mi][r] += __shfl_xor(p1[mi][r], mm);
          p2[mi][r] += __shfl_xor(p2[mi][r], mm);
        }
    if ((l & 15) == 0) {
      #pragma unroll
      for (int mi = 0; mi < 6; ++mi)
        #pragma unroll
        for (int r = 0; r < 4; ++r) {
          int m = mi * 16 + (l >> 4) * 4 + r;
          red[m * 16 + w * 2]     = p1[mi][r];
          red[m * 16 + w * 2 + 1] = p2[mi][r];
        }
    }
  }
  // ---- stage at_ into dead xs region (96*104 f16 = 1248 half8)
  for (int idx = t; idx < 1248; idx += 512)
    *(half8*)(at_ + idx * 8) = *(const half8*)(ATp + idx * 8);
  __syncthreads();

  if (t < 96) {
    float s1 = 0.f, s2 = 0.f;
    #pragma unroll
    for (int q = 0; q < 8; ++q) {
      s1 += red[t * 16 + q * 2];
      s2 += red[t * 16 + q * 2 + 1];
    }
    w1s[t] = s1;    // rows 92..95 are 0 (zero X rows)
    w2s[t] = s2;
  }
  __syncthreads();

  // ---- e0[i][k] = lrelu(Wh1[i]+Wh2[k]), zero-padded [96][104]
  for (int idx = t; idx < 96 * 128; idx += 512) {
    int i = idx >> 7, k = idx & 127;
    if (k < 104) {
      float v = (i < 92 && k < 92) ? lrelu(w1s[i] + w2s[k]) : 0.f;
      e0a[i * 104 + k] = (_Float16)v;
    }
  }
  BAR_LGKM();

  // ---- QK: e = lrelu(e0 @ A), mask, softmax; att back into e0a (waves 0-5)
  if (w < 6) {
    f32x4 ez = {0.f, 0.f, 0.f, 0.f};
    f32x4 eacc[6];
    #pragma unroll
    for (int ni = 0; ni < 6; ++ni) eacc[ni] = ez;
    #pragma unroll
    for (int ks = 0; ks < 3; ++ks) {
      half8 ea = *(const half8*)((const char*)e0a +
                 (16 * w + (l & 15)) * 208 + ks * 64 + (l >> 4) * 16);
      #pragma unroll
      for (int ni = 0; ni < 6; ++ni) {
        half8 bt = *(const half8*)((const char*)at_ +
                   (16 * ni + (l & 15)) * 208 + ks * 64 + (l >> 4) * 16);
        eacc[ni] = __builtin_amdgcn_mfma_f32_16x16x32_f16(ea, bt, eacc[ni], 0, 0, 0);
      }
    }
    float attv[4][6];
    #pragma unroll
    for (int r = 0; r < 4; ++r) {
      int i = 16 * w + (l >> 4) * 4 + r;
      float s[6]; float m = -3.0e38f;
      #pragma unroll
      for (int ni = 0; ni < 6; ++ni) {
        int j = ni * 16 + (l & 15);
        float e = lrelu(eacc[ni][r]);
        float sv = -3.0e38f;
        if (i < 92 && j < 92) {
          int avj = adj[((size_t)b * NNODE + i) * NNODE + j];
          sv = (avj > 0) ? e : -9.0e15f;
        }
        s[ni] = sv;
        m = fmaxf(m, sv);
      }
      #pragma unroll
      for (int mm = 1; mm < 16; mm <<= 1) m = fmaxf(m, __shfl_xor(m, mm));
      float sum = 0.f; float p[6];
      #pragma unroll
      for (int ni = 0; ni < 6; ++ni) {
        int j = ni * 16 + (l & 15);
        p[ni] = (i < 92 && j < 92) ? __expf(s[ni] - m) : 0.f;
        sum += p[ni];
      }
      #pragma unroll
      for (int mm = 1; mm < 16; mm <<= 1) sum += __shfl_xor(sum, mm);
      float rs = (i < 92) ? (1.0f / sum) : 0.f;
      #pragma unroll
      for (int ni = 0; ni < 6; ++ni) attv[r][ni] = p[ni] * rs;
    }
    #pragma unroll
    for (int r = 0; r < 4; ++r) {
      int i = 16 * w + (l >> 4) * 4 + r;
      #pragma unroll
      for (int ni = 0; ni < 6; ++ni)
        e0a[i * 104 + ni * 16 + (l & 15)] = (_Float16)attv[r][ni];
    }
  }
  BAR_LGKM();   // att visible

  // ---- PV: out = att @ Wh + bias ; wave w: 2 passes of 32 f-cols
  #pragma unroll 1
  for (int pp = 0; pp < 2; ++pp) {
    int f0 = pp * 256 + w * 32;
    half8 bfp[3][2];
    #pragma unroll
    for (int ks = 0; ks < 3; ++ks)
      #pragma unroll
      for (int ni = 0; ni < 2; ++ni)
        bfp[ks][ni] = *(const half8*)((const char*)whT +
            (f0 + ni * 16 + (l & 15)) * 208 + ks * 64 + (l >> 4) * 16);
    f32x4 pz = {0.f, 0.f, 0.f, 0.f};
    f32x4 pacc[6][2];
    #pragma unroll
    for (int mi = 0; mi < 6; ++mi)
      #pragma unroll
      for (int ni = 0; ni < 2; ++ni) pacc[mi][ni] = pz;
    #pragma unroll
    for (int ks = 0; ks < 3; ++ks) {
      half8 af[6];
      #pragma unroll
      for (int mi = 0; mi < 6; ++mi)
        af[mi] = *(const half8*)((const char*)e0a +
                 (16 * mi + (l & 15)) * 208 + ks * 64 + (l >> 4) * 16);
      #pragma unroll
      for (int mi = 0; mi < 6; ++mi)
        #pragma unroll
        for (int ni = 0; ni < 2; ++ni)
          pacc[mi][ni] = __builtin_amdgcn_mfma_f32_16x16x32_f16(
              af[mi], bfp[ks][ni], pacc[mi][ni], 0, 0, 0);
    }
    #pragma unroll
    for (int ni = 0; ni < 2; ++ni) {
      int fcol = f0 + ni * 16 + (l & 15);
      float bv = bias[fcol];
      #pragma unroll
      for (int mi = 0; mi < 6; ++mi)
        #pragma unroll
        for (int r = 0; r < 4; ++r) {
          int i = 16 * mi + (l >> 4) * 4 + r;
          if (i < 92)
            out[((size_t)b * NNODE + i) * FOUT + fcol] = pacc[mi][ni][r] + bv;
        }
    }
  }
}

// ---------------------------------------------------------------------------
extern "C" void kernel_launch(void* const* d_in, const int* in_sizes, int n_in,
                              void* d_out, int out_size, void* d_ws, size_t ws_size,
                              hipStream_t stream) {
  (void)in_sizes; (void)n_in; (void)out_size; (void)ws_size;
  const float* X    = (const float*)d_in[0];
  const int*   adj  = (const int*)d_in[1];
  const float* W    = (const float*)d_in[2];
  const float* av   = (const float*)d_in[3];
  const float* Am   = (const float*)d_in[4];
  const float* bias = (const float*)d_in[5];
  float* out = (float*)d_out;
  char* ws = (char*)d_ws;

  _Float16* WT  = (_Float16*)(ws);              // 1,048,576 B
  _Float16* ATp = (_Float16*)(ws + 1048576);    //    19,968 B

  prep_kernel<<<68, 256, 0, stream>>>(W, Am, WT, ATp);
  hipFuncSetAttribute((const void*)fused_kernel,
                      hipFuncAttributeMaxDynamicSharedMemorySize, 157952);
  fused_kernel<<<1024, 512, 157952, stream>>>(X, WT, ATp, adj, av, bias, out);
}